// Round 2
// baseline (81.328 us; speedup 1.0000x reference)
//
#include <hip/hip_runtime.h>
#include <hip/hip_bf16.h>

// Problem constants (fixed by reference)
#define NB    2
#define HW    25600      // 160*160
#define WDIM  160
#define NSTG  9

// ---- DPP add (full-rate VALU, no LDS pipe) ----
template <int CTRL>
__device__ __forceinline__ float dpp_add(float v) {
    int moved = __builtin_amdgcn_update_dpp(0, __float_as_int(v), CTRL, 0xf, 0xf, true);
    return v + __int_as_float(moved);
}

// sum over each 4-lane quad, broadcast to all 4 lanes — 2 quad_perm DPP adds.
__device__ __forceinline__ float reduce4(float v) {
    v = dpp_add<0xB1>(v);    // quad_perm [1,0,3,2] : xor 1
    v = dpp_add<0x4E>(v);    // quad_perm [2,3,0,1] : xor 2
    return v;
}

// Upper-triangle index for symmetric 9x9 H: row i start = 9i - i(i-1)/2
__device__ __forceinline__ constexpr int hidx(int i, int j) {
    return (i <= j) ? (9 * i - (i * (i - 1)) / 2 + (j - i))
                    : (9 * j - (j * (j - 1)) / 2 + (i - j));
}

// Fused kernel, Gram-space formulation.
// Key invariant: u = X a (u0 = X * (1/9)1, and u' = u*us + a*Xv' stays in col-span(X)).
// So the 9-stage loop runs in 9-D: c = H a (H = X^T X, 45 entries, built once),
// S = a.c, v' = v*(1-3bS) + b c, T = v'.v', a' = a*us + al v'.
// -> NO cross-lane ops in the stage loop (previous version: 90 reduce4 = 360 DPP+adds
//    on the serial chain). All reduce4 moved to the one-time H build.
// Layout: 4 lanes per pixel, 8 channels per lane -> 16 pixels/wave.
__global__ __launch_bounds__(256, 3) void fused_kernel(const float* __restrict__ x,
                                                       const float* __restrict__ head_w,
                                                       const float* __restrict__ tail_w,
                                                       const float* __restrict__ alphas,
                                                       const float* __restrict__ betas,
                                                       float* __restrict__ out) {
    int sub = threadIdx.x & 3;               // channel octet: channels 8*sub .. 8*sub+7
    int pid = blockIdx.x * 64 + (threadIdx.x >> 2);   // 64 pixels/block
    int b   = blockIdx.x / 400;              // 400 blocks per batch image
    int s2  = pid - b * HW;
    int c0  = sub * 8;

    // uniform per-stage constants -> scalar loads, zero VGPR cost
    float al[NSTG], be[NSTG];
#pragma unroll
    for (int i = 0; i < NSTG; ++i) { al[i] = alphas[i]; be[i] = betas[i]; }

    const float* xb0 = x + b * 3 * HW;

    // Unfold+reshape scramble (channel-preserving): for pixel s2, g = s2*9+k2,
    // kk = g/HW (constant per pixel except at most one wrap), l = g%HW.
    int g9  = s2 * 9;
    int kk0 = g9 / HW;
    int r0  = g9 - kk0 * HW;
    int h0  = r0 / WDIM;
    int w0  = r0 - h0 * WDIM;
    int ki0 = kk0 / 3;
    int dh0 = ki0 - 1,            dw0 = kk0 - ki0 * 3 - 1;
    int kk1 = kk0 + 1;
    int ki1 = kk1 / 3;
    int dh1 = ki1 - 1,            dw1 = kk1 - ki1 * 3 - 1;

    // ---- phase 1: all 9 gather addresses ----
    int p[9];
#pragma unroll
    for (int k2 = 0; k2 < 9; ++k2) {
        int r  = r0 + k2;
        int wn = w0 + k2;
        int cw = (wn >= WDIM);
        int w1 = cw ? wn - WDIM : wn;
        int h1 = h0 + cw;
        bool wr = (r >= HW);
        int h  = wr ? 0 : h1;
        int w  = wr ? r - HW : w1;
        int dh = wr ? dh1 : dh0;
        int dw = wr ? dw1 : dw0;
        int hh = min(max(h + dh, 0), 159);
        int ww = min(max(w + dw, 0), 159);
        p[k2]  = hh * WDIM + ww;
    }

    // ---- phase 2: all 27 gather loads issued together (one vmcnt window) ----
    float xv0[9], xv1[9], xv2[9];
#pragma unroll
    for (int k2 = 0; k2 < 9; ++k2) xv0[k2] = xb0[p[k2]];
#pragma unroll
    for (int k2 = 0; k2 < 9; ++k2) xv1[k2] = xb0[HW + p[k2]];
#pragma unroll
    for (int k2 = 0; k2 < 9; ++k2) xv2[k2] = xb0[2 * HW + p[k2]];

    // ---- phase 3: head conv, j-outer (only 3 head weights live at a time) ----
    float X[9][8];
#pragma unroll
    for (int j = 0; j < 8; ++j) {
        float hwj0 = head_w[(c0 + j) * 3 + 0];
        float hwj1 = head_w[(c0 + j) * 3 + 1];
        float hwj2 = head_w[(c0 + j) * 3 + 2];
#pragma unroll
        for (int k2 = 0; k2 < 9; ++k2)
            X[k2][j] = fmaxf(hwj0 * xv0[k2] + hwj1 * xv1[k2] + hwj2 * xv2[k2], 0.f);
    }

    // ---- one-time Gram matrix H = X^T X (45 upper-triangle entries) ----
    // Each lane sums its 8 channels; reduce4 completes the 32-channel sum.
    float Hm[45];
#pragma unroll
    for (int i = 0; i < 9; ++i) {
#pragma unroll
        for (int j = i; j < 9; ++j) {
            float hp = ((X[i][0] * X[j][0] + X[i][1] * X[j][1])
                      + (X[i][2] * X[j][2] + X[i][3] * X[j][3]))
                     + ((X[i][4] * X[j][4] + X[i][5] * X[j][5])
                      + (X[i][6] * X[j][6] + X[i][7] * X[j][7]));
            Hm[hidx(i, j)] = reduce4(hp);
        }
    }

    // init: v[k] = mean_c X (explicit; not derivable from H). a = (1/9)1 (u0 = X a, free).
    float v[9];
#pragma unroll
    for (int k = 0; k < 9; ++k) {
        float pr = ((X[k][0] + X[k][1]) + (X[k][2] + X[k][3]))
                 + ((X[k][4] + X[k][5]) + (X[k][6] + X[k][7]));
        v[k] = reduce4(pr) * (1.f / 32.f);
    }
    float a[9];
#pragma unroll
    for (int k = 0; k < 9; ++k) a[k] = (1.f / 9.f);

    // ---- 9 stages in 9-D Gram space: replicated per lane, zero cross-lane ----
#pragma unroll
    for (int i = 0; i < NSTG; ++i) {
        float beta  = be[i];
        float alpha = al[i];
        float b3 = 3.f * beta;
        float a3 = 3.f * alpha;
        // c = H a  (symmetric H, constant indices -> registers)
        float c[9];
#pragma unroll
        for (int r = 0; r < 9; ++r) {
            float t0 = Hm[hidx(r, 0)] * a[0] + Hm[hidx(r, 1)] * a[1];
            float t1 = Hm[hidx(r, 2)] * a[2] + Hm[hidx(r, 3)] * a[3];
            float t2 = Hm[hidx(r, 4)] * a[4] + Hm[hidx(r, 5)] * a[5];
            float t3 = Hm[hidx(r, 6)] * a[6] + Hm[hidx(r, 7)] * a[7];
            c[r] = ((t0 + t1) + (t2 + t3)) + Hm[hidx(r, 8)] * a[8];
        }
        // S = u.u = a.(H a)
        float S = (((a[0] * c[0] + a[1] * c[1]) + (a[2] * c[2] + a[3] * c[3]))
                +  ((a[4] * c[4] + a[5] * c[5]) + (a[6] * c[6] + a[7] * c[7])))
                +  a[8] * c[8];
        float vs = 1.f - b3 * S;
#pragma unroll
        for (int k = 0; k < 9; ++k)
            v[k] = v[k] * vs + beta * c[k];
        // T = v.v (tree)
        float T = (((v[0] * v[0] + v[1] * v[1]) + (v[2] * v[2] + v[3] * v[3]))
                +  ((v[4] * v[4] + v[5] * v[5]) + (v[6] * v[6] + v[7] * v[7])))
                +  v[8] * v[8];
        float us = 1.f - a3 * T;
#pragma unroll
        for (int k = 0; k < 9; ++k)
            a[k] = a[k] * us + alpha * v[k];
    }

    // ---- epilogue: u = X a ; UVc[c] = 3*u[c]*v[4] ; tail 1x1 conv + relu ----
    float v4 = v[4];
    float uvc[8];
#pragma unroll
    for (int j = 0; j < 8; ++j) {
        float t0 = X[0][j] * a[0] + X[1][j] * a[1];
        float t1 = X[2][j] * a[2] + X[3][j] * a[3];
        float t2 = X[4][j] * a[4] + X[5][j] * a[5];
        float t3 = X[6][j] * a[6] + X[7][j] * a[7];
        float u  = ((t0 + t1) + (t2 + t3)) + X[8][j] * a[8];
        uvc[j] = 3.f * u * v4;
    }
    float o[3];
#pragma unroll
    for (int oo = 0; oo < 3; ++oo) {
        const float* tw = tail_w + oo * 32 + c0;
        float pr = ((uvc[0] * tw[0] + uvc[1] * tw[1]) + (uvc[2] * tw[2] + uvc[3] * tw[3]))
                 + ((uvc[4] * tw[4] + uvc[5] * tw[5]) + (uvc[6] * tw[6] + uvc[7] * tw[7]));
        o[oo] = fmaxf(reduce4(pr), 0.f);
    }
    if (sub == 0) {
        float* op = out + b * 3 * HW + s2;
        op[0]      = o[0];
        op[HW]     = o[1];
        op[2 * HW] = o[2];
    }
}

extern "C" void kernel_launch(void* const* d_in, const int* in_sizes, int n_in,
                              void* d_out, int out_size, void* d_ws, size_t ws_size,
                              hipStream_t stream) {
    const float* x      = (const float*)d_in[0];
    const float* head_w = (const float*)d_in[1];
    const float* tail_w = (const float*)d_in[2];
    const float* alphas = (const float*)d_in[3];
    const float* betas  = (const float*)d_in[4];
    float*       out    = (float*)d_out;

    // NB*HW pixels * 4 lanes/pixel = 204800 threads -> 800 blocks of 256
    // (256,3): stage-live set is X[72]+H[45]+a/v/c[27] ~= 155 VGPR; capping at 128
    // would spill into the hot loop. Occupancy 3 vs 4 measured neutral (R0->R1).
    fused_kernel<<<dim3(NB * HW * 4 / 256), dim3(256), 0, stream>>>(
        x, head_w, tail_w, alphas, betas, out);
}

// Round 3
// 80.521 us; speedup vs baseline: 1.0100x; 1.0100x over previous
//
#include <hip/hip_runtime.h>
#include <hip/hip_bf16.h>

// Problem constants (fixed by reference)
#define NB    2
#define HW    25600      // 160*160
#define WDIM  160
#define NSTG  9

// ---- DPP add (full-rate VALU, no LDS pipe) ----
template <int CTRL>
__device__ __forceinline__ float dpp_add(float v) {
    int moved = __builtin_amdgcn_update_dpp(0, __float_as_int(v), CTRL, 0xf, 0xf, true);
    return v + __int_as_float(moved);
}

// sum over each 4-lane quad, broadcast to all 4 lanes — 2 quad_perm DPP adds.
__device__ __forceinline__ float reduce4(float v) {
    v = dpp_add<0xB1>(v);    // quad_perm [1,0,3,2] : xor 1
    v = dpp_add<0x4E>(v);    // quad_perm [2,3,0,1] : xor 2
    return v;
}

// Upper-triangle index for symmetric 9x9 H: row i start = 9i - i(i-1)/2
__device__ __forceinline__ constexpr int hidx(int i, int j) {
    return (i <= j) ? (9 * i - (i * (i - 1)) / 2 + (j - i))
                    : (9 * j - (j * (j - 1)) / 2 + (i - j));
}

// Fused kernel, Gram-space + tail-folded formulation.
//   u = X a  (invariant)  ->  9-stage loop runs on (H = X^T X, v, a) in 9-D.
//   out[oo] = relu(3*v4 * sum_k G[oo][k] a[k]),  G = tail_w @ X  (27 values).
// This revision removes X[72] liveness entirely (R2's spill suspect):
//   - build is channel-streamed: per channel compute Xc[9], accumulate
//     Hm[45] / v0p[9] / Gp[3][9], discard Xc.
//   - Gp is kept as per-lane PARTIAL (no reduce4 in build); since a is
//     quad-broadcast, reduce4 commutes to the final dot product.
// Loop live set ~105 VGPR (Hm45+Gp27+v9+a9+c9+temps) -> no spills at (256,3).
// Layout: 4 lanes per pixel, 8 channels per lane -> 16 pixels/wave.
__global__ __launch_bounds__(256, 3) void fused_kernel(const float* __restrict__ x,
                                                       const float* __restrict__ head_w,
                                                       const float* __restrict__ tail_w,
                                                       const float* __restrict__ alphas,
                                                       const float* __restrict__ betas,
                                                       float* __restrict__ out) {
    int sub = threadIdx.x & 3;               // channel octet: channels 8*sub .. 8*sub+7
    int pid = blockIdx.x * 64 + (threadIdx.x >> 2);   // 64 pixels/block
    int b   = blockIdx.x / 400;              // 400 blocks per batch image
    int s2  = pid - b * HW;
    int c0  = sub * 8;

    // uniform per-stage constants -> scalar loads, zero VGPR cost
    float al[NSTG], be[NSTG];
#pragma unroll
    for (int i = 0; i < NSTG; ++i) { al[i] = alphas[i]; be[i] = betas[i]; }

    const float* xb0 = x + b * 3 * HW;

    // Unfold+reshape scramble (channel-preserving): for pixel s2, g = s2*9+k2,
    // kk = g/HW (constant per pixel except at most one wrap), l = g%HW.
    int g9  = s2 * 9;
    int kk0 = g9 / HW;
    int r0  = g9 - kk0 * HW;
    int h0  = r0 / WDIM;
    int w0  = r0 - h0 * WDIM;
    int ki0 = kk0 / 3;
    int dh0 = ki0 - 1,            dw0 = kk0 - ki0 * 3 - 1;
    int kk1 = kk0 + 1;
    int ki1 = kk1 / 3;
    int dh1 = ki1 - 1,            dw1 = kk1 - ki1 * 3 - 1;

    // ---- phase 1: all 9 gather addresses ----
    int p[9];
#pragma unroll
    for (int k2 = 0; k2 < 9; ++k2) {
        int r  = r0 + k2;
        int wn = w0 + k2;
        int cw = (wn >= WDIM);
        int w1 = cw ? wn - WDIM : wn;
        int h1 = h0 + cw;
        bool wr = (r >= HW);
        int h  = wr ? 0 : h1;
        int w  = wr ? r - HW : w1;
        int dh = wr ? dh1 : dh0;
        int dw = wr ? dw1 : dw0;
        int hh = min(max(h + dh, 0), 159);
        int ww = min(max(w + dw, 0), 159);
        p[k2]  = hh * WDIM + ww;
    }

    // ---- phase 2: all 27 gather loads issued together (one vmcnt window) ----
    float xv0[9], xv1[9], xv2[9];
#pragma unroll
    for (int k2 = 0; k2 < 9; ++k2) xv0[k2] = xb0[p[k2]];
#pragma unroll
    for (int k2 = 0; k2 < 9; ++k2) xv1[k2] = xb0[HW + p[k2]];
#pragma unroll
    for (int k2 = 0; k2 < 9; ++k2) xv2[k2] = xb0[2 * HW + p[k2]];

    // ---- phase 3: channel-streamed build of Hm[45], v0p[9], Gp[3][9] ----
    float Hm[45], v0p[9], Gp[3][9];
    {   // channel j = 0 : initialize accumulators (saves 81 zero-movs)
        float w0h = head_w[c0 * 3 + 0];
        float w1h = head_w[c0 * 3 + 1];
        float w2h = head_w[c0 * 3 + 2];
        float Xc[9];
#pragma unroll
        for (int k = 0; k < 9; ++k)
            Xc[k] = fmaxf(w0h * xv0[k] + w1h * xv1[k] + w2h * xv2[k], 0.f);
#pragma unroll
        for (int i = 0; i < 9; ++i)
#pragma unroll
            for (int jj = i; jj < 9; ++jj)
                Hm[hidx(i, jj)] = Xc[i] * Xc[jj];
#pragma unroll
        for (int k = 0; k < 9; ++k) v0p[k] = Xc[k];
#pragma unroll
        for (int oo = 0; oo < 3; ++oo) {
            float tw = tail_w[oo * 32 + c0];
#pragma unroll
            for (int k = 0; k < 9; ++k) Gp[oo][k] = tw * Xc[k];
        }
    }
#pragma unroll
    for (int j = 1; j < 8; ++j) {
        float w0h = head_w[(c0 + j) * 3 + 0];
        float w1h = head_w[(c0 + j) * 3 + 1];
        float w2h = head_w[(c0 + j) * 3 + 2];
        float Xc[9];
#pragma unroll
        for (int k = 0; k < 9; ++k)
            Xc[k] = fmaxf(w0h * xv0[k] + w1h * xv1[k] + w2h * xv2[k], 0.f);
#pragma unroll
        for (int i = 0; i < 9; ++i)
#pragma unroll
            for (int jj = i; jj < 9; ++jj)
                Hm[hidx(i, jj)] += Xc[i] * Xc[jj];
#pragma unroll
        for (int k = 0; k < 9; ++k) v0p[k] += Xc[k];
#pragma unroll
        for (int oo = 0; oo < 3; ++oo) {
            float tw = tail_w[oo * 32 + c0 + j];
#pragma unroll
            for (int k = 0; k < 9; ++k) Gp[oo][k] += tw * Xc[k];
        }
    }

    // ---- complete the 32-channel sums: H broadcast, v0 broadcast ----
    // (45 independent reduce4s -> DPP hazards fully hidden by ILP)
#pragma unroll
    for (int t = 0; t < 45; ++t) Hm[t] = reduce4(Hm[t]);
    float v[9];
#pragma unroll
    for (int k = 0; k < 9; ++k) v[k] = reduce4(v0p[k]) * (1.f / 32.f);
    float a[9];
#pragma unroll
    for (int k = 0; k < 9; ++k) a[k] = (1.f / 9.f);

    // ---- 9 stages in 9-D Gram space: replicated per lane, zero cross-lane ----
#pragma unroll
    for (int i = 0; i < NSTG; ++i) {
        float beta  = be[i];
        float alpha = al[i];
        float b3 = 3.f * beta;
        float a3 = 3.f * alpha;
        // c = H a  (symmetric H, constant indices -> registers)
        float c[9];
#pragma unroll
        for (int r = 0; r < 9; ++r) {
            float t0 = Hm[hidx(r, 0)] * a[0] + Hm[hidx(r, 1)] * a[1];
            float t1 = Hm[hidx(r, 2)] * a[2] + Hm[hidx(r, 3)] * a[3];
            float t2 = Hm[hidx(r, 4)] * a[4] + Hm[hidx(r, 5)] * a[5];
            float t3 = Hm[hidx(r, 6)] * a[6] + Hm[hidx(r, 7)] * a[7];
            c[r] = ((t0 + t1) + (t2 + t3)) + Hm[hidx(r, 8)] * a[8];
        }
        // S = u.u = a.(H a)
        float S = (((a[0] * c[0] + a[1] * c[1]) + (a[2] * c[2] + a[3] * c[3]))
                +  ((a[4] * c[4] + a[5] * c[5]) + (a[6] * c[6] + a[7] * c[7])))
                +  a[8] * c[8];
        float vs = 1.f - b3 * S;
#pragma unroll
        for (int k = 0; k < 9; ++k)
            v[k] = v[k] * vs + beta * c[k];
        // T = v.v (tree)
        float T = (((v[0] * v[0] + v[1] * v[1]) + (v[2] * v[2] + v[3] * v[3]))
                +  ((v[4] * v[4] + v[5] * v[5]) + (v[6] * v[6] + v[7] * v[7])))
                +  v[8] * v[8];
        float us = 1.f - a3 * T;
#pragma unroll
        for (int k = 0; k < 9; ++k)
            a[k] = a[k] * us + alpha * v[k];
    }

    // ---- epilogue: out[oo] = relu(3*v4 * reduce4(Gp[oo].a)) ----
    float v4 = v[4];
    float o[3];
#pragma unroll
    for (int oo = 0; oo < 3; ++oo) {
        float t0 = Gp[oo][0] * a[0] + Gp[oo][1] * a[1];
        float t1 = Gp[oo][2] * a[2] + Gp[oo][3] * a[3];
        float t2 = Gp[oo][4] * a[4] + Gp[oo][5] * a[5];
        float t3 = Gp[oo][6] * a[6] + Gp[oo][7] * a[7];
        float d  = ((t0 + t1) + (t2 + t3)) + Gp[oo][8] * a[8];
        float r  = reduce4(d);
        o[oo] = fmaxf(3.f * v4 * r, 0.f);
    }
    if (sub == 0) {
        float* op = out + b * 3 * HW + s2;
        op[0]      = o[0];
        op[HW]     = o[1];
        op[2 * HW] = o[2];
    }
}

extern "C" void kernel_launch(void* const* d_in, const int* in_sizes, int n_in,
                              void* d_out, int out_size, void* d_ws, size_t ws_size,
                              hipStream_t stream) {
    const float* x      = (const float*)d_in[0];
    const float* head_w = (const float*)d_in[1];
    const float* tail_w = (const float*)d_in[2];
    const float* alphas = (const float*)d_in[3];
    const float* betas  = (const float*)d_in[4];
    float*       out    = (float*)d_out;

    // NB*HW pixels * 4 lanes/pixel = 204800 threads -> 800 blocks of 256
    // (256,3): loop live-set ~105 VGPR, well under the ~168 cap -> no spills.
    // Occupancy 3 vs 4 blocks/CU measured neutral (R0->R1).
    fused_kernel<<<dim3(NB * HW * 4 / 256), dim3(256), 0, stream>>>(
        x, head_w, tail_w, alphas, betas, out);
}

// Round 4
// 76.298 us; speedup vs baseline: 1.0659x; 1.0554x over previous
//
#include <hip/hip_runtime.h>

// Problem constants (fixed by reference)
#define NB    2
#define HW    25600      // 160*160
#define WDIM  160
#define NSTG  9

// raw DPP move (quad_perm), 0-fill irrelevant (all lanes active)
template <int CTRL>
__device__ __forceinline__ float dpp_mov(float v) {
    return __int_as_float(__builtin_amdgcn_update_dpp(0, __float_as_int(v), CTRL, 0xf, 0xf, true));
}
// quad_perm controls: 0xB1 = [1,0,3,2] (xor1), 0x4E = [2,3,0,1] (xor2)

// Upper-triangle index for symmetric 9x9 H: row i start = 9i - i(i-1)/2
__device__ __forceinline__ constexpr int hidx(int i, int j) {
    return (i <= j) ? (9 * i - (i * (i - 1)) / 2 + (j - i))
                    : (9 * j - (j * (j - 1)) / 2 + (i - j));
}

// Transpose-Gram kernel: one wave (64 threads) handles 64 pixels.
//  phase A (x4 sub-batches of 16 px, quad-per-pixel channel-split):
//    build per-lane partials of H[45] (=X^T X), v0[9] (=col-mean basis),
//    G[27] (=tail_w @ X, tail folded in), then a 4-lane BUTTERFLY
//    transpose-reduce: lane s of each quad ends with the 32-channel TOTAL of
//    entry 4g+s -> single ds_write. LDS holds 81 totals per pixel (stride 85,
//    odd -> conflict-free reads).
//  phase B: lane l owns pixel l: reads H+v0, runs the 9-stage 9-D dynamics
//    ONCE (previously replicated x4 per quad = 75% redundant).
//  phase C: epilogue per owner lane: out[oo] = relu(3*v4*sum_k G[oo][k]a[k]),
//    G read from LDS; stores are lane-consecutive -> fully coalesced.
// Per-pixel lane-inst: ~6.4k vs R1's ~11k (-42%).
__global__ __launch_bounds__(64) void fused_kernel(const float* __restrict__ x,
                                                   const float* __restrict__ head_w,
                                                   const float* __restrict__ tail_w,
                                                   const float* __restrict__ alphas,
                                                   const float* __restrict__ betas,
                                                   float* __restrict__ out) {
    const int lane = threadIdx.x;            // 0..63, block = 1 wave
    const int sub  = lane & 3;               // quad position / channel octet
    const int c0   = sub * 8;
    const bool m1  = (lane & 1) != 0;
    const bool m2  = (lane & 2) != 0;

    __shared__ float lds[64 * 85];           // 21.8 KB: 64 pixels x 85 (81 used)

    // uniform per-stage constants
    float al[NSTG], be[NSTG];
#pragma unroll
    for (int i = 0; i < NSTG; ++i) { al[i] = alphas[i]; be[i] = betas[i]; }

    // hoisted weights (shared across the 4 sub-batches)
    float hw[8][3];
#pragma unroll
    for (int j = 0; j < 8; ++j)
#pragma unroll
        for (int ci = 0; ci < 3; ++ci) hw[j][ci] = head_w[(c0 + j) * 3 + ci];
    float tw[3][8];
#pragma unroll
    for (int oo = 0; oo < 3; ++oo)
#pragma unroll
        for (int j = 0; j < 8; ++j) tw[oo][j] = tail_w[oo * 32 + c0 + j];

    const int bimg    = blockIdx.x / 400;            // 400 blocks per image (64 px each)
    const int base_s2 = blockIdx.x * 64 - bimg * HW; // first pixel of this wave
    const float* xb0  = x + bimg * 3 * HW;

    // ---- phase A: build 64 pixels in 4 sub-batches of 16 ----
#pragma unroll 1
    for (int bb = 0; bb < 4; ++bb) {
        const int s2 = base_s2 + bb * 16 + (lane >> 2);

        // unfold+reshape scramble (verbatim from the proven kernel)
        int g9  = s2 * 9;
        int kk0 = g9 / HW;
        int r0  = g9 - kk0 * HW;
        int h0  = r0 / WDIM;
        int w0  = r0 - h0 * WDIM;
        int ki0 = kk0 / 3;
        int dh0 = ki0 - 1,            dw0 = kk0 - ki0 * 3 - 1;
        int kk1 = kk0 + 1;
        int ki1 = kk1 / 3;
        int dh1 = ki1 - 1,            dw1 = kk1 - ki1 * 3 - 1;

        int p[9];
#pragma unroll
        for (int k2 = 0; k2 < 9; ++k2) {
            int r  = r0 + k2;
            int wn = w0 + k2;
            int cw = (wn >= WDIM);
            int w1 = cw ? wn - WDIM : wn;
            int h1 = h0 + cw;
            bool wr = (r >= HW);
            int h  = wr ? 0 : h1;
            int w  = wr ? r - HW : w1;
            int dh = wr ? dh1 : dh0;
            int dw = wr ? dw1 : dw0;
            int hh = min(max(h + dh, 0), 159);
            int ww = min(max(w + dw, 0), 159);
            p[k2]  = hh * WDIM + ww;
        }

        // all 27 gather loads in one window
        float xv0[9], xv1[9], xv2[9];
#pragma unroll
        for (int k2 = 0; k2 < 9; ++k2) xv0[k2] = xb0[p[k2]];
#pragma unroll
        for (int k2 = 0; k2 < 9; ++k2) xv1[k2] = xb0[HW + p[k2]];
#pragma unroll
        for (int k2 = 0; k2 < 9; ++k2) xv2[k2] = xb0[2 * HW + p[k2]];

        // channel-streamed build of per-lane partials
        float Hp[45], v0p[9], Gpp[27];
        {   // channel 0 initializes
            float Xc[9];
#pragma unroll
            for (int k = 0; k < 9; ++k)
                Xc[k] = fmaxf(hw[0][0] * xv0[k] + hw[0][1] * xv1[k] + hw[0][2] * xv2[k], 0.f);
#pragma unroll
            for (int i = 0; i < 9; ++i)
#pragma unroll
                for (int jj = i; jj < 9; ++jj)
                    Hp[hidx(i, jj)] = Xc[i] * Xc[jj];
#pragma unroll
            for (int k = 0; k < 9; ++k) v0p[k] = Xc[k];
#pragma unroll
            for (int oo = 0; oo < 3; ++oo)
#pragma unroll
                for (int k = 0; k < 9; ++k) Gpp[oo * 9 + k] = tw[oo][0] * Xc[k];
        }
#pragma unroll
        for (int j = 1; j < 8; ++j) {
            float Xc[9];
#pragma unroll
            for (int k = 0; k < 9; ++k)
                Xc[k] = fmaxf(hw[j][0] * xv0[k] + hw[j][1] * xv1[k] + hw[j][2] * xv2[k], 0.f);
#pragma unroll
            for (int i = 0; i < 9; ++i)
#pragma unroll
                for (int jj = i; jj < 9; ++jj)
                    Hp[hidx(i, jj)] += Xc[i] * Xc[jj];
#pragma unroll
            for (int k = 0; k < 9; ++k) v0p[k] += Xc[k];
#pragma unroll
            for (int oo = 0; oo < 3; ++oo)
#pragma unroll
                for (int k = 0; k < 9; ++k) Gpp[oo * 9 + k] += tw[oo][j] * Xc[k];
        }

        // entry map: 0..44 H, 45..53 v0, 54..80 G(oo*9+k), 81..83 pad
        auto getP = [&](int e) -> float {
            if (e < 45) return Hp[e];
            if (e < 54) return v0p[e - 45];
            if (e < 81) return Gpp[e - 54];
            return 0.f;
        };

        // butterfly transpose-reduce (4 entries/group): lane s ends with the
        // 32-channel total of entry 4g+s -> one ds_write each.
        const int slotbase = (bb * 16 + (lane >> 2)) * 85;
#pragma unroll
        for (int g = 0; g < 21; ++g) {
            float P0 = getP(4 * g + 0), P1 = getP(4 * g + 1);
            float P2 = getP(4 * g + 2), P3 = getP(4 * g + 3);
            // round A (xor2): entry halves meet across lane-distance 2
            float a0 = m2 ? P2 : P0;
            float s0 = m2 ? P0 : P2;
            a0 += dpp_mov<0x4E>(s0);
            float a1 = m2 ? P3 : P1;
            float s1 = m2 ? P1 : P3;
            a1 += dpp_mov<0x4E>(s1);
            // round B (xor1): finish; lane s holds total of entry 4g+s
            float fin = m1 ? a1 : a0;
            float sB  = m1 ? a0 : a1;
            fin += dpp_mov<0xB1>(sB);
            lds[slotbase + 4 * g + sub] = fin;
        }
    }

    __syncthreads();

    // ---- phase B: lane owns pixel `lane`; 9-stage dynamics in 9-D ----
    const int my = lane * 85;
    float Hm[45];
#pragma unroll
    for (int e = 0; e < 45; ++e) Hm[e] = lds[my + e];
    float v[9];
#pragma unroll
    for (int k = 0; k < 9; ++k) v[k] = lds[my + 45 + k] * (1.f / 32.f);
    float a[9];
#pragma unroll
    for (int k = 0; k < 9; ++k) a[k] = (1.f / 9.f);

#pragma unroll
    for (int i = 0; i < NSTG; ++i) {
        float beta  = be[i];
        float alpha = al[i];
        float b3 = 3.f * beta;
        float a3 = 3.f * alpha;
        float c[9];
#pragma unroll
        for (int r = 0; r < 9; ++r) {
            float t0 = Hm[hidx(r, 0)] * a[0] + Hm[hidx(r, 1)] * a[1];
            float t1 = Hm[hidx(r, 2)] * a[2] + Hm[hidx(r, 3)] * a[3];
            float t2 = Hm[hidx(r, 4)] * a[4] + Hm[hidx(r, 5)] * a[5];
            float t3 = Hm[hidx(r, 6)] * a[6] + Hm[hidx(r, 7)] * a[7];
            c[r] = ((t0 + t1) + (t2 + t3)) + Hm[hidx(r, 8)] * a[8];
        }
        float S = (((a[0] * c[0] + a[1] * c[1]) + (a[2] * c[2] + a[3] * c[3]))
                +  ((a[4] * c[4] + a[5] * c[5]) + (a[6] * c[6] + a[7] * c[7])))
                +  a[8] * c[8];
        float vs = 1.f - b3 * S;
#pragma unroll
        for (int k = 0; k < 9; ++k)
            v[k] = v[k] * vs + beta * c[k];
        float T = (((v[0] * v[0] + v[1] * v[1]) + (v[2] * v[2] + v[3] * v[3]))
                +  ((v[4] * v[4] + v[5] * v[5]) + (v[6] * v[6] + v[7] * v[7])))
                +  v[8] * v[8];
        float us = 1.f - a3 * T;
#pragma unroll
        for (int k = 0; k < 9; ++k)
            a[k] = a[k] * us + alpha * v[k];
    }

    // ---- phase C: epilogue, owner lane writes 3 outputs (coalesced) ----
    float v4 = v[4];
    float* op = out + bimg * 3 * HW + (base_s2 + lane);
#pragma unroll
    for (int oo = 0; oo < 3; ++oo) {
        const int gb = my + 54 + oo * 9;
        float t0 = lds[gb + 0] * a[0] + lds[gb + 1] * a[1];
        float t1 = lds[gb + 2] * a[2] + lds[gb + 3] * a[3];
        float t2 = lds[gb + 4] * a[4] + lds[gb + 5] * a[5];
        float t3 = lds[gb + 6] * a[6] + lds[gb + 7] * a[7];
        float d  = ((t0 + t1) + (t2 + t3)) + lds[gb + 8] * a[8];
        op[oo * HW] = fmaxf(3.f * v4 * d, 0.f);
    }
}

extern "C" void kernel_launch(void* const* d_in, const int* in_sizes, int n_in,
                              void* d_out, int out_size, void* d_ws, size_t ws_size,
                              hipStream_t stream) {
    const float* x      = (const float*)d_in[0];
    const float* head_w = (const float*)d_in[1];
    const float* tail_w = (const float*)d_in[2];
    const float* alphas = (const float*)d_in[3];
    const float* betas  = (const float*)d_in[4];
    float*       out    = (float*)d_out;

    // 51200 pixels / 64 px-per-wave = 800 blocks of 64 threads (1 wave each).
    // LDS 21.8 KB/block; stride 85 (odd) -> conflict-free per-pixel reads.
    fused_kernel<<<dim3(NB * HW / 64), dim3(64), 0, stream>>>(
        x, head_w, tail_w, alphas, betas, out);
}